// Round 2
// baseline (454.199 us; speedup 1.0000x reference)
//
#include <hip/hip_runtime.h>
#include <math.h>

#define NSTEPS 18
#define NS 128      // N_CES*B
#define CHW 12288   // 3*64*64
#define HW 4096     // 64*64
#define NCLS 1000
#define WR 50       // max LDS window rows per block (16 + 2*18, clipped to 50)

// XOR swizzle for 256B-row-stride LDS tile: spread rows across 16B chunks
#define SWZ(off) ((off) ^ ((((off) >> 8) & 7) << 4))

struct StepC { float c_skip, c_out, c_in, inv_t, ce, two_dt, nc, pad; };
struct Steps { StepC s[NSTEPS]; float t0; };

// ---- Sampler: 4 blocks per sample (16 output rows each), halo-redundant ----
__global__ __launch_bounds__(448, 4)
void sampler_kernel(const float* __restrict__ x, const float* __restrict__ latents,
                    const float* __restrict__ noise, const float* __restrict__ Wn_g,
                    const float* __restrict__ bn_g, float* __restrict__ Aout, Steps S)
{
    __shared__ float xs[3 * WR * 64];
    __shared__ float Wn[81];
    __shared__ float bn[3];
    char* xb = (char*)xs;
    const int tid = threadIdx.x;
    const int n = blockIdx.x >> 2;       // sample
    const int q = blockIdx.x & 3;        // quarter
    const int base = q << 4;             // first output row
    const int w0 = max(0, base - 18);
    const int w1 = min(64, base + 34);
    const int wsize = w1 - w0;           // 34 or 50

    if (tid < 81) Wn[tid] = Wn_g[tid];
    if (tid < 3)  bn[tid] = bn_g[tid];

    const float t0 = S.t0;
    const float* lat = latents + (size_t)n * CHW;

    // stage x0 = latents * t0 for the window (swizzled float4 stores)
    #pragma unroll
    for (int ci = 0; ci < 3; ++ci)
        for (int u = tid; u < wsize * 16; u += 448) {
            const int lr2 = u >> 4, c4 = (u & 15) << 2;
            float4 v = *reinterpret_cast<const float4*>(lat + ci * HW + (w0 + lr2) * 64 + c4);
            v.x *= t0; v.y *= t0; v.z *= t0; v.w *= t0;
            const int off = (ci * 3200 + lr2 * 64 + c4) << 2;
            *reinterpret_cast<float4*>(xb + SWZ(off)) = v;
        }

    const int lr = tid >> 3;            // local row 0..55 (valid < wsize)
    const int sc = tid & 7;
    const int cbase = sc << 3;
    const int gr = w0 + lr;             // global row owned by this thread
    const bool rowv = (lr < wsize);

    // preload mu = 2*x - 1 for this thread's row
    const float* xin = x + (size_t)(n & 63) * CHW;
    float mu[3][8];
    if (rowv) {
        #pragma unroll
        for (int co = 0; co < 3; ++co) {
            const float* mb = xin + co * HW + gr * 64 + cbase;
            float4 m0 = *reinterpret_cast<const float4*>(mb);
            float4 m1 = *reinterpret_cast<const float4*>(mb + 4);
            mu[co][0] = 2.f*m0.x - 1.f; mu[co][1] = 2.f*m0.y - 1.f;
            mu[co][2] = 2.f*m0.z - 1.f; mu[co][3] = 2.f*m0.w - 1.f;
            mu[co][4] = 2.f*m1.x - 1.f; mu[co][5] = 2.f*m1.y - 1.f;
            mu[co][6] = 2.f*m1.z - 1.f; mu[co][7] = 2.f*m1.w - 1.f;
        }
    }
    __syncthreads();

    for (int step = 0; step < NSTEPS; ++step) {
        const StepC c = S.s[step];
        const int lo = base - 17 + step;
        const int hi = base + 33 - step;
        const bool active = rowv && (gr >= lo) && (gr < hi);
        float xnew[3][8];

        if (active) {
            float acc[3][8];
            #pragma unroll
            for (int co = 0; co < 3; ++co)
                #pragma unroll
                for (int j = 0; j < 8; ++j) acc[co][j] = 0.f;
            float xsave[3][8];

            #pragma unroll
            for (int ci = 0; ci < 3; ++ci) {
                float in[3][10];
                #pragma unroll
                for (int dh = 0; dh < 3; ++dh) {
                    const int grr = gr + dh - 1;
                    if (grr >= 0 && grr < 64) {
                        const int lrr = lr + dh - 1;
                        const int bo = (ci * 3200 + lrr * 64 + cbase) << 2;
                        float4 a = *reinterpret_cast<const float4*>(xb + SWZ(bo));
                        float4 b = *reinterpret_cast<const float4*>(xb + SWZ(bo + 16));
                        in[dh][1] = a.x; in[dh][2] = a.y; in[dh][3] = a.z; in[dh][4] = a.w;
                        in[dh][5] = b.x; in[dh][6] = b.y; in[dh][7] = b.z; in[dh][8] = b.w;
                        in[dh][0] = (cbase > 0)  ? *reinterpret_cast<const float*>(xb + SWZ(bo - 4))  : 0.f;
                        in[dh][9] = (cbase < 56) ? *reinterpret_cast<const float*>(xb + SWZ(bo + 32)) : 0.f;
                    } else {
                        #pragma unroll
                        for (int p = 0; p < 10; ++p) in[dh][p] = 0.f;
                    }
                }
                #pragma unroll
                for (int j = 0; j < 8; ++j) xsave[ci][j] = in[1][j + 1];

                #pragma unroll
                for (int co = 0; co < 3; ++co)
                    #pragma unroll
                    for (int dh = 0; dh < 3; ++dh)
                        #pragma unroll
                        for (int dw = 0; dw < 3; ++dw) {
                            const float w = Wn[((co * 3 + ci) * 3 + dh) * 3 + dw];
                            #pragma unroll
                            for (int j = 0; j < 8; ++j)
                                acc[co][j] = fmaf(w, in[dh][j + dw], acc[co][j]);
                        }
            }

            // EDM update
            const float* nz = noise + ((size_t)(step * NS + n)) * CHW;
            #pragma unroll
            for (int co = 0; co < 3; ++co) {
                float eps[8];
                if (step < NSTEPS - 2) {
                    const float* nb = nz + co * HW + gr * 64 + cbase;
                    float4 e0 = *reinterpret_cast<const float4*>(nb);
                    float4 e1 = *reinterpret_cast<const float4*>(nb + 4);
                    eps[0]=e0.x; eps[1]=e0.y; eps[2]=e0.z; eps[3]=e0.w;
                    eps[4]=e1.x; eps[5]=e1.y; eps[6]=e1.z; eps[7]=e1.w;
                } else {
                    #pragma unroll
                    for (int j = 0; j < 8; ++j) eps[j] = 0.f;
                }
                #pragma unroll
                for (int j = 0; j < 8; ++j) {
                    const float xc = xsave[co][j];
                    const float f = fmaf(c.c_in, acc[co][j], bn[co]);
                    const float den = c.c_skip * xc + c.c_out * f;
                    const float dx = (den - xc) * c.inv_t + c.ce * (mu[co][j] - xc);
                    xnew[co][j] = fmaf(c.two_dt, dx, fmaf(c.nc, eps[j], xc));
                }
            }
        }
        __syncthreads();
        if (active) {
            #pragma unroll
            for (int co = 0; co < 3; ++co) {
                const int wo = (co * 3200 + lr * 64 + cbase) << 2;
                *reinterpret_cast<float4*>(xb + SWZ(wo)) =
                    make_float4(xnew[co][0], xnew[co][1], xnew[co][2], xnew[co][3]);
                *reinterpret_cast<float4*>(xb + SWZ(wo + 16)) =
                    make_float4(xnew[co][4], xnew[co][5], xnew[co][6], xnew[co][7]);
            }
        }
        __syncthreads();
    }

    // write A = (x_final + 1)/2 for the 16 owned rows
    float* Ao = Aout + (size_t)n * CHW;
    #pragma unroll
    for (int ci = 0; ci < 3; ++ci)
        for (int u = tid; u < 16 * 16; u += 448) {
            const int r16 = u >> 4, c4 = (u & 15) << 2;
            const int glr = base + r16 - w0;
            const int off = (ci * 3200 + glr * 64 + c4) << 2;
            float4 v = *reinterpret_cast<const float4*>(xb + SWZ(off));
            v.x = (v.x + 1.f) * 0.5f; v.y = (v.y + 1.f) * 0.5f;
            v.z = (v.z + 1.f) * 0.5f; v.w = (v.w + 1.f) * 0.5f;
            *reinterpret_cast<float4*>(Ao + ci * HW + (base + r16) * 64 + c4) = v;
        }
}

// ---------------- GEMM: C[128][1000] partials, K split across blocks ----------------
__global__ __launch_bounds__(256)
void gemm_kernel(const float* __restrict__ A, const float* __restrict__ Wc,
                 float* __restrict__ part, int bkc)
{
    __shared__ float As[16][132];   // [k][row], padded
    __shared__ float Ws[16][64];    // [k][col]
    const int tid = threadIdx.x;
    const int ct = blockIdx.x & 15;      // col tile (16 x 64 = 1024 >= 1000)
    const int kc = blockIdx.x >> 4;      // k chunk
    const int c0 = ct << 6;
    const int k0 = kc * bkc;
    const int rg = tid >> 4;             // 0..15 -> rows rg*8..+8
    const int cg = tid & 15;             // 0..15 -> cols cg*4..+4

    float acc[8][4];
    #pragma unroll
    for (int i = 0; i < 8; ++i)
        #pragma unroll
        for (int j = 0; j < 4; ++j) acc[i][j] = 0.f;

    for (int kk = 0; kk < bkc; kk += 16) {
        #pragma unroll
        for (int p = 0; p < 2; ++p) {
            const int u = tid + p * 256;
            const int row = u >> 2;
            const int ks4 = (u & 3) << 2;
            float4 v = *reinterpret_cast<const float4*>(A + (size_t)row * CHW + k0 + kk + ks4);
            As[ks4 + 0][row] = v.x; As[ks4 + 1][row] = v.y;
            As[ks4 + 2][row] = v.z; As[ks4 + 3][row] = v.w;
        }
        {
            const int wr = tid >> 4;
            const int wcc = (tid & 15) << 2;
            const int col = c0 + wcc;
            float4 v = make_float4(0.f, 0.f, 0.f, 0.f);
            if (col < NCLS)
                v = *reinterpret_cast<const float4*>(Wc + (size_t)(k0 + kk + wr) * NCLS + col);
            *reinterpret_cast<float4*>(&Ws[wr][wcc]) = v;
        }
        __syncthreads();
        #pragma unroll
        for (int k = 0; k < 16; ++k) {
            const float4 a0 = *reinterpret_cast<const float4*>(&As[k][rg * 8]);
            const float4 a1 = *reinterpret_cast<const float4*>(&As[k][rg * 8 + 4]);
            const float4 b  = *reinterpret_cast<const float4*>(&Ws[k][cg * 4]);
            const float av[8] = {a0.x, a0.y, a0.z, a0.w, a1.x, a1.y, a1.z, a1.w};
            const float bv[4] = {b.x, b.y, b.z, b.w};
            #pragma unroll
            for (int i = 0; i < 8; ++i)
                #pragma unroll
                for (int j = 0; j < 4; ++j)
                    acc[i][j] = fmaf(av[i], bv[j], acc[i][j]);
        }
        __syncthreads();
    }

    float* pp = part + (size_t)kc * NS * NCLS;
    #pragma unroll
    for (int i = 0; i < 8; ++i) {
        const int row = rg * 8 + i;
        const int col = c0 + (cg << 2);
        if (col < NCLS)
            *reinterpret_cast<float4*>(pp + (size_t)row * NCLS + col) =
                make_float4(acc[i][0], acc[i][1], acc[i][2], acc[i][3]);
    }
}

// ---------------- Reduce partials + bias + logsumexp over the 2 CEs ----------------
__global__ __launch_bounds__(256)
void lse_kernel(const float* __restrict__ part, const float* __restrict__ bcls,
                float* __restrict__ out, int ks)
{
    const int i = blockIdx.x * 256 + threadIdx.x;
    if (i >= 64 * NCLS) return;
    const int b = i / NCLS;
    const int k = i - b * NCLS;
    float l0 = bcls[k], l1 = bcls[k];
    for (int kc = 0; kc < ks; ++kc) {
        l0 += part[(size_t)kc * NS * NCLS + (size_t)b * NCLS + k];
        l1 += part[(size_t)kc * NS * NCLS + (size_t)(b + 64) * NCLS + k];
    }
    const float m = fmaxf(l0, l1);
    out[i] = m + logf(expf(l0 - m) + expf(l1 - m)) - 0.69314718055994530942f;
}

extern "C" void kernel_launch(void* const* d_in, const int* in_sizes, int n_in,
                              void* d_out, int out_size, void* d_ws, size_t ws_size,
                              hipStream_t stream) {
    const float* x       = (const float*)d_in[0];
    const float* latents = (const float*)d_in[1];
    const float* noise   = (const float*)d_in[2];
    const float* W_net   = (const float*)d_in[3];
    const float* b_net   = (const float*)d_in[4];
    const float* W_cls   = (const float*)d_in[5];
    const float* b_cls   = (const float*)d_in[6];
    float* out = (float*)d_out;
    float* ws  = (float*)d_ws;

    float* Amat = ws;                       // 128*12288 floats
    float* part = ws + (size_t)NS * CHW;    // KS*128*1000 floats

    // Karras sigma schedule in float64 (matches numpy), cast to f32
    Steps S;
    const double smin = pow(0.002, 1.0 / 7.0), smax = pow(80.0, 1.0 / 7.0);
    float tsf[NSTEPS + 1];
    for (int i = 0; i < NSTEPS; ++i) {
        double v = smax + (double)i / (double)(NSTEPS - 1) * (smin - smax);
        tsf[i] = (float)pow(v, 7.0);
    }
    tsf[NSTEPS] = 0.f;
    S.t0 = tsf[0];
    for (int i = 0; i < NSTEPS; ++i) {
        const float t = tsf[i], tn = tsf[i + 1];
        const float s2 = t * t, denom = s2 + 0.25f;
        StepC c;
        c.c_skip = 0.25f / denom;
        c.c_out  = t * 0.5f / sqrtf(denom);
        c.c_in   = 1.0f / sqrtf(denom);
        c.inv_t  = 1.0f / t;
        c.ce     = t / (0.04f + s2);
        const float dt = t - tn;
        c.two_dt = 2.f * dt;
        c.nc     = sqrtf(2.f * t * dt);
        c.pad    = 0.f;
        S.s[i] = c;
    }

    // pick largest K-split that fits in workspace
    int KSr = 32;
    while (KSr > 1 && (size_t)(NS * CHW + (size_t)KSr * NS * NCLS) * 4 > ws_size) KSr >>= 1;
    const int bkc = CHW / KSr;

    sampler_kernel<<<NS * 4, 448, 0, stream>>>(x, latents, noise, W_net, b_net, Amat, S);
    gemm_kernel<<<16 * KSr, 256, 0, stream>>>(Amat, W_cls, part, bkc);
    lse_kernel<<<(64 * NCLS + 255) / 256, 256, 0, stream>>>(part, b_cls, out, KSr);
}

// Round 3
// 110.394 us; speedup vs baseline: 4.1144x; 4.1144x over previous
//
#include <hip/hip_runtime.h>
#include <math.h>

#define NSTEPS 18
#define NS 128      // N_CES*B
#define CHW 12288   // 3*64*64
#define HW 4096     // 64*64
#define NCLS 1000
#define WR 50       // LDS window rows per block (32 owned + 18 halo each side, clipped)

// XOR swizzle for 256B-row-stride LDS tile (16B-granular, b128-compatible)
#define SWZ(off) ((off) ^ ((((off) >> 8) & 7) << 4))

struct StepC { float c_skip, c_out, c_in, inv_t, ce, two_dt, nc, pad; };
struct Steps { StepC s[NSTEPS]; float t0; };

typedef __attribute__((ext_vector_type(8))) short v8s;
typedef __attribute__((ext_vector_type(4))) float v4f;

__device__ __forceinline__ unsigned short f2bf(float f) {
    unsigned int u = __float_as_uint(f);
    unsigned int r = (u + 0x7FFFu + ((u >> 16) & 1u)) >> 16;   // RNE
    return (unsigned short)r;
}

// ---- Sampler: 2 blocks per sample (32 output rows each), halo-redundant ----
__global__ __launch_bounds__(448, 2)
void sampler_kernel(const float* __restrict__ x, const float* __restrict__ latents,
                    const float* __restrict__ noise, const float* __restrict__ Wn_g,
                    const float* __restrict__ bn_g, unsigned short* __restrict__ Aout, Steps S)
{
    __shared__ float xs[3 * WR * 64];     // 37.5 KB
    __shared__ float Wn[81];
    __shared__ float bn[3];
    char* xb = (char*)xs;
    const int tid = threadIdx.x;
    const int n = blockIdx.x >> 1;
    const int q = blockIdx.x & 1;
    const int base = q << 5;             // first owned row (0 or 32)
    const int w0 = (base - 18 > 0) ? base - 18 : 0;
    const int w1 = (base + 50 < 64) ? base + 50 : 64;
    const int wsize = w1 - w0;           // 50

    if (tid < 81) Wn[tid] = Wn_g[tid];
    if (tid < 3)  bn[tid] = bn_g[tid];

    const float t0 = S.t0;
    const float* lat = latents + (size_t)n * CHW;

    // stage x0 = latents * t0 into swizzled LDS window
    #pragma unroll
    for (int ci = 0; ci < 3; ++ci)
        for (int u = tid; u < wsize * 16; u += 448) {
            const int lr2 = u >> 4, c4 = (u & 15) << 2;
            float4 v = *reinterpret_cast<const float4*>(lat + ci * HW + (w0 + lr2) * 64 + c4);
            v.x *= t0; v.y *= t0; v.z *= t0; v.w *= t0;
            const int off = (ci * 3200 + lr2 * 64 + c4) << 2;
            *reinterpret_cast<float4*>(xb + SWZ(off)) = v;
        }

    const int lr = tid >> 3;            // local row slot
    const int sc = tid & 7;
    const int cbase = sc << 3;
    const int gr = w0 + lr;
    const bool rowv = (lr < wsize);
    __syncthreads();

    // own-row state in registers
    float xc[3][8];
    if (rowv) {
        #pragma unroll
        for (int ci = 0; ci < 3; ++ci) {
            const int bo = (ci * 3200 + lr * 64 + cbase) << 2;
            float4 a = *reinterpret_cast<const float4*>(xb + SWZ(bo));
            float4 b = *reinterpret_cast<const float4*>(xb + SWZ(bo + 16));
            xc[ci][0]=a.x; xc[ci][1]=a.y; xc[ci][2]=a.z; xc[ci][3]=a.w;
            xc[ci][4]=b.x; xc[ci][5]=b.y; xc[ci][6]=b.z; xc[ci][7]=b.w;
        }
    }

    // mu = 2*x - 1 for own row
    const float* xin = x + (size_t)(n & 63) * CHW;
    float mu[3][8];
    if (rowv) {
        #pragma unroll
        for (int co = 0; co < 3; ++co) {
            const float* mb = xin + co * HW + gr * 64 + cbase;
            float4 m0 = *reinterpret_cast<const float4*>(mb);
            float4 m1 = *reinterpret_cast<const float4*>(mb + 4);
            mu[co][0] = 2.f*m0.x - 1.f; mu[co][1] = 2.f*m0.y - 1.f;
            mu[co][2] = 2.f*m0.z - 1.f; mu[co][3] = 2.f*m0.w - 1.f;
            mu[co][4] = 2.f*m1.x - 1.f; mu[co][5] = 2.f*m1.y - 1.f;
            mu[co][6] = 2.f*m1.z - 1.f; mu[co][7] = 2.f*m1.w - 1.f;
        }
    }

    for (int step = 0; step < NSTEPS; ++step) {
        const StepC c = S.s[step];
        const int lo = base - 17 + step;
        const int hi = base + 49 - step;
        const bool active = rowv && (gr >= lo) && (gr < hi);

        if (active) {
            float acc[3][8];
            #pragma unroll
            for (int co = 0; co < 3; ++co)
                #pragma unroll
                for (int j = 0; j < 8; ++j) acc[co][j] = 0.f;

            #pragma unroll
            for (int ci = 0; ci < 3; ++ci) {
                float in0[10], in2[10], cen[10];
                // dh = 0 (row gr-1)
                if (gr - 1 >= 0) {
                    const int bo = (ci * 3200 + (lr - 1) * 64 + cbase) << 2;
                    float4 a = *reinterpret_cast<const float4*>(xb + SWZ(bo));
                    float4 b = *reinterpret_cast<const float4*>(xb + SWZ(bo + 16));
                    in0[1]=a.x; in0[2]=a.y; in0[3]=a.z; in0[4]=a.w;
                    in0[5]=b.x; in0[6]=b.y; in0[7]=b.z; in0[8]=b.w;
                    in0[0] = (sc > 0) ? __shfl_up(in0[8], 1) : 0.f;
                    in0[9] = (sc < 7) ? __shfl_down(in0[1], 1) : 0.f;
                } else {
                    #pragma unroll
                    for (int p = 0; p < 10; ++p) in0[p] = 0.f;
                }
                // dh = 2 (row gr+1)
                if (gr + 1 < 64) {
                    const int bo = (ci * 3200 + (lr + 1) * 64 + cbase) << 2;
                    float4 a = *reinterpret_cast<const float4*>(xb + SWZ(bo));
                    float4 b = *reinterpret_cast<const float4*>(xb + SWZ(bo + 16));
                    in2[1]=a.x; in2[2]=a.y; in2[3]=a.z; in2[4]=a.w;
                    in2[5]=b.x; in2[6]=b.y; in2[7]=b.z; in2[8]=b.w;
                    in2[0] = (sc > 0) ? __shfl_up(in2[8], 1) : 0.f;
                    in2[9] = (sc < 7) ? __shfl_down(in2[1], 1) : 0.f;
                } else {
                    #pragma unroll
                    for (int p = 0; p < 10; ++p) in2[p] = 0.f;
                }
                // dh = 1 (own row, from registers)
                cen[0] = (sc > 0) ? __shfl_up(xc[ci][7], 1) : 0.f;
                cen[9] = (sc < 7) ? __shfl_down(xc[ci][0], 1) : 0.f;
                #pragma unroll
                for (int j = 0; j < 8; ++j) cen[j + 1] = xc[ci][j];

                #pragma unroll
                for (int co = 0; co < 3; ++co) {
                    const int wb = (co * 3 + ci) * 9;
                    #pragma unroll
                    for (int dw = 0; dw < 3; ++dw) {
                        const float w0t = Wn[wb + dw];
                        const float w1t = Wn[wb + 3 + dw];
                        const float w2t = Wn[wb + 6 + dw];
                        #pragma unroll
                        for (int j = 0; j < 8; ++j) {
                            acc[co][j] = fmaf(w0t, in0[j + dw], acc[co][j]);
                            acc[co][j] = fmaf(w1t, cen[j + dw], acc[co][j]);
                            acc[co][j] = fmaf(w2t, in2[j + dw], acc[co][j]);
                        }
                    }
                }
            }

            // EDM update (xc is the center/current value)
            const float* nz = noise + ((size_t)(step * NS + n)) * CHW;
            #pragma unroll
            for (int co = 0; co < 3; ++co) {
                float eps[8];
                if (step < NSTEPS - 2) {
                    const float* nb = nz + co * HW + gr * 64 + cbase;
                    float4 e0 = *reinterpret_cast<const float4*>(nb);
                    float4 e1 = *reinterpret_cast<const float4*>(nb + 4);
                    eps[0]=e0.x; eps[1]=e0.y; eps[2]=e0.z; eps[3]=e0.w;
                    eps[4]=e1.x; eps[5]=e1.y; eps[6]=e1.z; eps[7]=e1.w;
                } else {
                    #pragma unroll
                    for (int j = 0; j < 8; ++j) eps[j] = 0.f;
                }
                #pragma unroll
                for (int j = 0; j < 8; ++j) {
                    const float xv = xc[co][j];
                    const float f = fmaf(c.c_in, acc[co][j], bn[co]);
                    const float den = c.c_skip * xv + c.c_out * f;
                    const float dx = (den - xv) * c.inv_t + c.ce * (mu[co][j] - xv);
                    xc[co][j] = fmaf(c.two_dt, dx, fmaf(c.nc, eps[j], xv));
                }
            }
        }
        __syncthreads();
        if (active) {
            #pragma unroll
            for (int co = 0; co < 3; ++co) {
                const int wo = (co * 3200 + lr * 64 + cbase) << 2;
                *reinterpret_cast<float4*>(xb + SWZ(wo)) =
                    make_float4(xc[co][0], xc[co][1], xc[co][2], xc[co][3]);
                *reinterpret_cast<float4*>(xb + SWZ(wo + 16)) =
                    make_float4(xc[co][4], xc[co][5], xc[co][6], xc[co][7]);
            }
        }
        __syncthreads();
    }

    // write A = (x_final + 1)/2 as bf16 for the 32 owned rows
    unsigned short* Ao = Aout + (size_t)n * CHW;
    for (int u = tid; u < 3 * 32 * 16; u += 448) {
        const int ci = u >> 9;
        const int rem = u & 511;
        const int r = rem >> 4, c4 = (rem & 15) << 2;
        const int lrow = base + r - w0;
        const int off = (ci * 3200 + lrow * 64 + c4) << 2;
        float4 v = *reinterpret_cast<const float4*>(xb + SWZ(off));
        ushort4 o;
        o.x = f2bf((v.x + 1.f) * 0.5f); o.y = f2bf((v.y + 1.f) * 0.5f);
        o.z = f2bf((v.z + 1.f) * 0.5f); o.w = f2bf((v.w + 1.f) * 0.5f);
        *reinterpret_cast<ushort4*>(Ao + ci * HW + (base + r) * 64 + c4) = o;
    }
}

// ---- GEMM: bf16 MFMA, A bf16 from ws, Wc f32 converted in-register, no LDS ----
__global__ __launch_bounds__(256)
void gemm_kernel(const unsigned short* __restrict__ Abf, const float* __restrict__ Wc,
                 float* __restrict__ part, int bkc)
{
    const int tid = threadIdx.x;
    const int wv = tid >> 6;
    const int lane = tid & 63;
    const int lrow = lane & 15;
    const int lk8 = (lane >> 4) << 3;
    const int ct = blockIdx.x & 15;
    const int kc = blockIdx.x >> 4;
    const int c0 = ct << 6;
    const int k0 = kc * bkc;

    v4f acc[2][4];
    #pragma unroll
    for (int rt = 0; rt < 2; ++rt)
        #pragma unroll
        for (int c4 = 0; c4 < 4; ++c4) acc[rt][c4] = (v4f)0.f;

    #pragma unroll 2
    for (int kk = 0; kk < bkc; kk += 32) {
        const int kb = k0 + kk + lk8;
        v8s a[2];
        #pragma unroll
        for (int rt = 0; rt < 2; ++rt)
            a[rt] = *reinterpret_cast<const v8s*>(Abf + (size_t)(wv * 32 + rt * 16 + lrow) * CHW + kb);
        v8s b[4];
        #pragma unroll
        for (int c4 = 0; c4 < 4; ++c4) {
            const int col = c0 + c4 * 16 + lrow;
            const bool cv = (col < NCLS);
            #pragma unroll
            for (int j = 0; j < 8; ++j) {
                const float f = cv ? Wc[(size_t)(kb + j) * NCLS + col] : 0.f;
                b[c4][j] = (short)f2bf(f);
            }
        }
        #pragma unroll
        for (int rt = 0; rt < 2; ++rt)
            #pragma unroll
            for (int c4 = 0; c4 < 4; ++c4)
                acc[rt][c4] = __builtin_amdgcn_mfma_f32_16x16x32_bf16(a[rt], b[c4], acc[rt][c4], 0, 0, 0);
    }

    float* pp = part + (size_t)kc * NS * NCLS;
    #pragma unroll
    for (int rt = 0; rt < 2; ++rt)
        #pragma unroll
        for (int c4 = 0; c4 < 4; ++c4) {
            const int col = c0 + c4 * 16 + lrow;
            if (col < NCLS) {
                #pragma unroll
                for (int r = 0; r < 4; ++r) {
                    const int row = wv * 32 + rt * 16 + (lane >> 4) * 4 + r;
                    pp[(size_t)row * NCLS + col] = acc[rt][c4][r];
                }
            }
        }
}

// ---- Reduce partials + bias + logsumexp over the 2 CEs ----
__global__ __launch_bounds__(256)
void lse_kernel(const float* __restrict__ part, const float* __restrict__ bcls,
                float* __restrict__ out, int ks)
{
    const int i = blockIdx.x * 256 + threadIdx.x;
    if (i >= 64 * NCLS) return;
    const int b = i / NCLS;
    const int k = i - b * NCLS;
    float l0 = bcls[k], l1 = bcls[k];
    for (int kc = 0; kc < ks; ++kc) {
        l0 += part[(size_t)kc * NS * NCLS + (size_t)b * NCLS + k];
        l1 += part[(size_t)kc * NS * NCLS + (size_t)(b + 64) * NCLS + k];
    }
    const float m = fmaxf(l0, l1);
    out[i] = m + logf(expf(l0 - m) + expf(l1 - m)) - 0.69314718055994530942f;
}

extern "C" void kernel_launch(void* const* d_in, const int* in_sizes, int n_in,
                              void* d_out, int out_size, void* d_ws, size_t ws_size,
                              hipStream_t stream) {
    const float* x       = (const float*)d_in[0];
    const float* latents = (const float*)d_in[1];
    const float* noise   = (const float*)d_in[2];
    const float* W_net   = (const float*)d_in[3];
    const float* b_net   = (const float*)d_in[4];
    const float* W_cls   = (const float*)d_in[5];
    const float* b_cls   = (const float*)d_in[6];
    float* out = (float*)d_out;

    unsigned short* Amat = (unsigned short*)d_ws;            // 128*12288 bf16 = 3.15 MB
    const size_t amat_bytes = (size_t)NS * CHW * 2;
    float* part = (float*)((char*)d_ws + amat_bytes);

    // Karras sigma schedule in float64 (matches numpy), cast to f32
    Steps S;
    const double smin = pow(0.002, 1.0 / 7.0), smax = pow(80.0, 1.0 / 7.0);
    float tsf[NSTEPS + 1];
    for (int i = 0; i < NSTEPS; ++i) {
        double v = smax + (double)i / (double)(NSTEPS - 1) * (smin - smax);
        tsf[i] = (float)pow(v, 7.0);
    }
    tsf[NSTEPS] = 0.f;
    S.t0 = tsf[0];
    for (int i = 0; i < NSTEPS; ++i) {
        const float t = tsf[i], tn = tsf[i + 1];
        const float s2 = t * t, denom = s2 + 0.25f;
        StepC c;
        c.c_skip = 0.25f / denom;
        c.c_out  = t * 0.5f / sqrtf(denom);
        c.c_in   = 1.0f / sqrtf(denom);
        c.inv_t  = 1.0f / t;
        c.ce     = t / (0.04f + s2);
        const float dt = t - tn;
        c.two_dt = 2.f * dt;
        c.nc     = sqrtf(2.f * t * dt);
        c.pad    = 0.f;
        S.s[i] = c;
    }

    // K-split sized to workspace
    int KS = 32;
    while (KS > 1 && amat_bytes + (size_t)KS * NS * NCLS * 4 > ws_size) KS >>= 1;
    const int bkc = CHW / KS;

    sampler_kernel<<<NS * 2, 448, 0, stream>>>(x, latents, noise, W_net, b_net, Amat, S);
    gemm_kernel<<<16 * KS, 256, 0, stream>>>(Amat, W_cls, part, bkc);
    lse_kernel<<<(64 * NCLS + 255) / 256, 256, 0, stream>>>(part, b_cls, out, KS);
}